// Round 1
// baseline (1408.326 us; speedup 1.0000x reference)
//
#include <hip/hip_runtime.h>
#include <math.h>

#define NSLOPE 0.2f

// ============================================================
// GEMM: C[M,Nn] = act(A[M,K] @ B[K,Nn] + bias (+ rank1 terms))
// BM=BN=64, BK=32, 256 threads, 4x4 micro-tile per thread.
// If u1 != nullptr: adds x0*u1[col] + x1*u2[col] per row (rank-1
// folded x1/x2 contributions for fc1), where x0/x1 come from xrow.
// ============================================================
__global__ __launch_bounds__(256)
void gemm_tile(const float* __restrict__ A, int lda,
               const float* __restrict__ B, int ldb,
               float* __restrict__ C, int ldc,
               int M, int K,
               const float* __restrict__ bias,
               int do_relu,
               const float* __restrict__ u1,
               const float* __restrict__ u2,
               const float* __restrict__ xrow, int xld)
{
    __shared__ __align__(16) float As[32][68];   // [k][m], row=272B=17*16B -> float4-aligned
    __shared__ __align__(16) float Bs[32][68];   // [k][n]
    const int tid = threadIdx.x;
    const int tx = tid & 15;    // col group (4 cols each)
    const int ty = tid >> 4;    // row group (4 rows each)
    const int m0 = blockIdx.x * 64;
    const int n0 = blockIdx.y * 64;

    float acc[4][4];
#pragma unroll
    for (int i = 0; i < 4; i++)
#pragma unroll
        for (int j = 0; j < 4; j++) acc[i][j] = 0.f;

    for (int k0 = 0; k0 < K; k0 += 32) {
        // stage A tile 64x32 (transposed into As[k][m])
#pragma unroll
        for (int i = tid; i < 64 * 32; i += 256) {
            int r = i >> 5, c = i & 31;
            int g = m0 + r;
            As[c][r] = (g < M) ? A[(size_t)g * lda + k0 + c] : 0.f;
        }
        // stage B tile 32x64
#pragma unroll
        for (int i = tid; i < 32 * 64; i += 256) {
            int kk = i >> 6, n = i & 63;
            Bs[kk][n] = B[(size_t)(k0 + kk) * ldb + n0 + n];
        }
        __syncthreads();
#pragma unroll
        for (int kk = 0; kk < 32; kk++) {
            float4 a4 = *(const float4*)&As[kk][ty * 4];
            float4 b4 = *(const float4*)&Bs[kk][tx * 4];
            float av[4] = {a4.x, a4.y, a4.z, a4.w};
            float bv[4] = {b4.x, b4.y, b4.z, b4.w};
#pragma unroll
            for (int i = 0; i < 4; i++)
#pragma unroll
                for (int j = 0; j < 4; j++)
                    acc[i][j] += av[i] * bv[j];
        }
        __syncthreads();
    }

    // epilogue
#pragma unroll
    for (int i = 0; i < 4; i++) {
        int g = m0 + ty * 4 + i;
        if (g >= M) continue;
        float x0 = 0.f, x1v = 0.f;
        if (u1) {
            x0  = xrow[(size_t)g * xld];
            x1v = xrow[(size_t)g * xld + 1];
        }
        float4 out;
        float* o = &out.x;
#pragma unroll
        for (int j = 0; j < 4; j++) {
            int col = n0 + tx * 4 + j;
            float v = acc[i][j];
            if (bias) v += bias[col];
            if (u1) v += x0 * u1[col] + x1v * u2[col];
            if (do_relu) v = v > 0.f ? v : 0.f;
            o[j] = v;
        }
        *(float4*)&C[(size_t)g * ldc + n0 + tx * 4] = out;
    }
}

// ============================================================
// u1[j] = sum_k w1[k]*fc1w[k,j]; u2[j] = sum_k w2[k]*fc1w[64+k,j]
// cb[j] = fc1b[j] + sum_k b1[k]*fc1w[k,j] + sum_k b2[k]*fc1w[64+k,j]
// ============================================================
__global__ void prep_u(const float* __restrict__ w1, const float* __restrict__ b1,
                       const float* __restrict__ w2, const float* __restrict__ b2,
                       const float* __restrict__ fc1w, const float* __restrict__ fc1b,
                       float* __restrict__ u1, float* __restrict__ u2, float* __restrict__ cb)
{
    int j = threadIdx.x + blockIdx.x * blockDim.x;
    if (j >= 384) return;
    float s1 = 0.f, s2 = 0.f, c = fc1b[j];
    for (int k = 0; k < 64; k++) {
        float wv = fc1w[k * 384 + j];
        s1 += w1[k] * wv; c += b1[k] * wv;
    }
    for (int k = 0; k < 64; k++) {
        float wv = fc1w[(64 + k) * 384 + j];
        s2 += w2[k] * wv; c += b2[k] * wv;
    }
    u1[j] = s1; u2[j] = s2; cb[j] = c;
}

// ============================================================
// per-node alpha_s = h[n,:]·a_src, alpha_d = h[n,:]·a_dst
// one wave (64 lanes) per node, butterfly reduce
// ============================================================
__global__ __launch_bounds__(256)
void alpha_kernel(const float* __restrict__ h, const float* __restrict__ asrc,
                  const float* __restrict__ adst, float* __restrict__ alpha_s,
                  float* __restrict__ alpha_d, int N)
{
    int node = blockIdx.x * 4 + (threadIdx.x >> 6);
    int lane = threadIdx.x & 63;
    if (node >= N) return;
    float v = h[(size_t)node * 64 + lane];
    float ps = v * asrc[lane];
    float pd = v * adst[lane];
#pragma unroll
    for (int off = 32; off > 0; off >>= 1) {
        ps += __shfl_xor(ps, off);
        pd += __shfl_xor(pd, off);
    }
    if (lane == 0) { alpha_s[node] = ps; alpha_d[node] = pd; }
}

// ============================================================
// edge scatter: for each edge (incl. self-loops at e>=E):
//   ex = exp(leaky_relu(alpha_s[src]+alpha_d[dst]))   [no max-shift: e in ~[-2.5,10], safe]
//   denom[dst] += ex;  acc[dst,:] += ex * h[src,:]
// wave handles 64 edges: lane-parallel scalar phase, then 64
// broadcast iterations for the 64-wide vector gather+atomic.
// ============================================================
__global__ __launch_bounds__(256)
void edge_scatter(const int* __restrict__ ei, int E, int N,
                  const float* __restrict__ alpha_s, const float* __restrict__ alpha_d,
                  const float* __restrict__ h,
                  float* __restrict__ acc, float* __restrict__ denom)
{
    const int total = E + N;
    const int wave = blockIdx.x * 4 + (threadIdx.x >> 6);
    const int lane = threadIdx.x & 63;
    const int base = wave * 64;
    if (base >= total) return;

    int e = base + lane;
    int s = 0, d = 0;
    float ex = 0.f;
    if (e < total) {
        if (e < E) { s = ei[e]; d = ei[E + e]; }
        else       { s = e - E; d = s; }
        float v = alpha_s[s] + alpha_d[d];
        v = v > 0.f ? v : NSLOPE * v;
        ex = expf(v);
        atomicAdd(&denom[d], ex);
    }
    int nval = total - base; if (nval > 64) nval = 64;
    for (int j = 0; j < nval; j++) {
        int ss = __shfl(s, j);
        int dd = __shfl(d, j);
        float exj = __shfl(ex, j);
        float hv = h[(size_t)ss * 64 + lane];
        atomicAdd(&acc[(size_t)dd * 64 + lane], exj * hv);
    }
}

// ============================================================
// x3[n,d] = acc[n,d]/(denom[n]+1e-16) + gat_b[d]  (in place)
// ============================================================
__global__ __launch_bounds__(256)
void normalize_kernel(float* __restrict__ acc, const float* __restrict__ denom,
                      const float* __restrict__ gatb, int N)
{
    int idx = blockIdx.x * 256 + threadIdx.x;
    if (idx >= N * 64) return;
    int n = idx >> 6, d = idx & 63;
    acc[idx] = acc[idx] / (denom[n] + 1e-16f) + gatb[d];
}

extern "C" void kernel_launch(void* const* d_in, const int* in_sizes, int n_in,
                              void* d_out, int out_size, void* d_ws, size_t ws_size,
                              hipStream_t stream)
{
    const float* x      = (const float*)d_in[0];
    const int*   ei     = (const int*)d_in[1];   // jax default: int64 request -> int32 arrays
    const float* w1     = (const float*)d_in[2];
    const float* b1     = (const float*)d_in[3];
    const float* w2     = (const float*)d_in[4];
    const float* b2     = (const float*)d_in[5];
    const float* gat_w  = (const float*)d_in[6];
    const float* gat_as = (const float*)d_in[7];
    const float* gat_ad = (const float*)d_in[8];
    const float* gat_b  = (const float*)d_in[9];
    const float* fc1w   = (const float*)d_in[10];
    const float* fc1b   = (const float*)d_in[11];
    const float* fc2w   = (const float*)d_in[12];
    const float* fc2b   = (const float*)d_in[13];
    const float* fc3w   = (const float*)d_in[14];
    const float* fc3b   = (const float*)d_in[15];

    const int N = in_sizes[0] / 130;
    const int E = in_sizes[1] / 2;
    float* out = (float*)d_out;

    // ---- workspace layout (floats) ----
    float* ws = (float*)d_ws;
    size_t off = 0;
    float* h     = ws + off; off += (size_t)N * 64;   // GAT h
    float* acc   = ws + off; off += (size_t)N * 64;   // unnormalized aggregation -> x3
    float* denom = ws + off; off += (size_t)N;        // softmax denominator (contiguous w/ acc)
    float* alS   = ws + off; off += (size_t)N;
    float* alD   = ws + off; off += (size_t)N;
    float* u1    = ws + off; off += 512;
    float* u2    = ws + off; off += 512;
    float* cb    = ws + off; off += 512;
    size_t fixed = off;
    // chunked MLP intermediates: 512 floats per node-row (384 + 128)
    size_t avail_rows = (ws_size / sizeof(float) > fixed)
                        ? (ws_size / sizeof(float) - fixed) / 512 : 0;
    int CHUNK = 16384;
    if ((size_t)CHUNK > avail_rows) CHUNK = (int)((avail_rows / 64) * 64);
    if (CHUNK < 64) CHUNK = 64;   // last-resort; assume ws is big enough
    float* h1c = ws + off; off += (size_t)CHUNK * 384;
    float* h2c = ws + off; off += (size_t)CHUNK * 128;

    // zero acc + denom (adjacent -> single memset; ws is 0xAA-poisoned each call)
    hipMemsetAsync(acc, 0, ((size_t)N * 64 + N) * sizeof(float), stream);

    // rank-1 folds for fc1
    prep_u<<<3, 128, 0, stream>>>(w1, b1, w2, b2, fc1w, fc1b, u1, u2, cb);

    const int mt = (N + 63) / 64;

    // h = x[:,2:] @ gat_w   (A = x+2, lda=130; K=128, Nn=64)
    gemm_tile<<<dim3(mt, 1), 256, 0, stream>>>(x + 2, 130, gat_w, 64, h, 64,
                                               N, 128, nullptr, 0,
                                               nullptr, nullptr, nullptr, 0);

    alpha_kernel<<<(N + 3) / 4, 256, 0, stream>>>(h, gat_as, gat_ad, alS, alD, N);

    const int total = E + N;
    const int waves = (total + 63) / 64;
    edge_scatter<<<(waves + 3) / 4, 256, 0, stream>>>(ei, E, N, alS, alD, h, acc, denom);

    normalize_kernel<<<(N * 64 + 255) / 256, 256, 0, stream>>>(acc, denom, gat_b, N);

    // MLP, chunked over nodes
    for (int start = 0; start < N; start += CHUNK) {
        int mc = N - start; if (mc > CHUNK) mc = CHUNK;
        int mtc = (mc + 63) / 64;
        // fc1: relu(x3 @ fc1_w[128:192,:] + x0*u1 + x1*u2 + cb) -> h1c [mc,384]
        gemm_tile<<<dim3(mtc, 6), 256, 0, stream>>>(acc + (size_t)start * 64, 64,
                                                    fc1w + (size_t)128 * 384, 384,
                                                    h1c, 384, mc, 64,
                                                    cb, 1, u1, u2,
                                                    x + (size_t)start * 130, 130);
        // fc2: relu(h1 @ fc2_w + fc2_b) -> h2c [mc,128]
        gemm_tile<<<dim3(mtc, 2), 256, 0, stream>>>(h1c, 384, fc2w, 128,
                                                    h2c, 128, mc, 384,
                                                    fc2b, 1, nullptr, nullptr, nullptr, 0);
        // fc3: h2 @ fc3_w + fc3_b -> out [mc,64]
        gemm_tile<<<dim3(mtc, 1), 256, 0, stream>>>(h2c, 128, fc3w, 64,
                                                    out + (size_t)start * 64, 64, mc, 128,
                                                    fc3b, 0, nullptr, nullptr, nullptr, 0);
    }
}

// Round 2
// 1244.687 us; speedup vs baseline: 1.1315x; 1.1315x over previous
//
#include <hip/hip_runtime.h>
#include <math.h>

#define NSLOPE 0.2f

// ============================================================
// GEMM: C[M,N] = act(A[M,K] @ B[K,N] + bias (+ rank1 terms))
// BM=128, BN in {64,128}, BK=32, 256 threads.
// Micro-tile: 8 rows x TN cols per thread (TN = BN/16).
// Col mapping: j<4 -> tx*4+j ; j>=4 -> 64+tx*4+(j-4)  (2-way LDS
// aliasing only -> free per m136).
// ============================================================
template<int BN>
__global__ __launch_bounds__(256)
void gemm_tile(const float* __restrict__ A, int lda,
               const float* __restrict__ B, int ldb,
               float* __restrict__ C, int ldc,
               int M, int K,
               const float* __restrict__ bias, int do_relu,
               const float* __restrict__ u1, const float* __restrict__ u2,
               const float* __restrict__ xrow, int xld)
{
    constexpr int TN = BN / 16;
    __shared__ __align__(16) float As[32][132];
    __shared__ __align__(16) float Bs[32][BN + 4];
    const int tid = threadIdx.x;
    const int tx = tid & 15;          // col group
    const int ty = tid >> 4;          // row group (0..15), 8 rows each
    const int m0 = blockIdx.x * 128;
    const int n0 = blockIdx.y * BN;

    float acc[8][TN];
#pragma unroll
    for (int i = 0; i < 8; i++)
#pragma unroll
        for (int j = 0; j < TN; j++) acc[i][j] = 0.f;

    for (int k0 = 0; k0 < K; k0 += 32) {
        // stage A tile 128x32, transposed into As[k][m]
#pragma unroll
        for (int i = tid; i < 128 * 32; i += 256) {
            int r = i >> 5, c = i & 31;
            int g = m0 + r;
            As[c][r] = (g < M) ? A[(size_t)g * lda + k0 + c] : 0.f;
        }
        // stage B tile 32xBN
#pragma unroll
        for (int i = tid; i < 32 * BN; i += 256) {
            int kk = (BN == 128) ? (i >> 7) : (i >> 6);
            int n  = i & (BN - 1);
            Bs[kk][n] = B[(size_t)(k0 + kk) * ldb + n0 + n];
        }
        __syncthreads();
#pragma unroll
        for (int kk = 0; kk < 32; kk++) {
            float4 a0 = *(const float4*)&As[kk][ty * 8];
            float4 a1 = *(const float4*)&As[kk][ty * 8 + 4];
            float av[8] = {a0.x, a0.y, a0.z, a0.w, a1.x, a1.y, a1.z, a1.w};
            float bv[TN];
            {
                float4 b0 = *(const float4*)&Bs[kk][tx * 4];
                bv[0] = b0.x; bv[1] = b0.y; bv[2] = b0.z; bv[3] = b0.w;
            }
            if (TN == 8) {
                float4 b1 = *(const float4*)&Bs[kk][64 + tx * 4];
                bv[4] = b1.x; bv[5] = b1.y; bv[6] = b1.z; bv[7] = b1.w;
            }
#pragma unroll
            for (int i = 0; i < 8; i++)
#pragma unroll
                for (int j = 0; j < TN; j++)
                    acc[i][j] += av[i] * bv[j];
        }
        __syncthreads();
    }

    // epilogue
#pragma unroll
    for (int i = 0; i < 8; i++) {
        int g = m0 + ty * 8 + i;
        if (g >= M) continue;
        float x0 = 0.f, x1v = 0.f;
        if (u1) {
            x0  = xrow[(size_t)g * xld];
            x1v = xrow[(size_t)g * xld + 1];
        }
#pragma unroll
        for (int half = 0; half < TN / 4; half++) {
            float4 out;
            float* o = &out.x;
#pragma unroll
            for (int j = 0; j < 4; j++) {
                int col = n0 + half * 64 + tx * 4 + j;
                float v = acc[i][half * 4 + j];
                if (bias) v += bias[col];
                if (u1) v += x0 * u1[col] + x1v * u2[col];
                if (do_relu) v = v > 0.f ? v : 0.f;
                o[j] = v;
            }
            *(float4*)&C[(size_t)g * ldc + n0 + half * 64 + tx * 4] = out;
        }
    }
}

// ============================================================
// rank-1 folds of x1/x2 paths into fc1
// ============================================================
__global__ void prep_u(const float* __restrict__ w1, const float* __restrict__ b1,
                       const float* __restrict__ w2, const float* __restrict__ b2,
                       const float* __restrict__ fc1w, const float* __restrict__ fc1b,
                       float* __restrict__ u1, float* __restrict__ u2, float* __restrict__ cb)
{
    int j = threadIdx.x + blockIdx.x * blockDim.x;
    if (j >= 384) return;
    float s1 = 0.f, s2 = 0.f, c = fc1b[j];
    for (int k = 0; k < 64; k++) {
        float wv = fc1w[k * 384 + j];
        s1 += w1[k] * wv; c += b1[k] * wv;
    }
    for (int k = 0; k < 64; k++) {
        float wv = fc1w[(64 + k) * 384 + j];
        s2 += w2[k] * wv; c += b2[k] * wv;
    }
    u1[j] = s1; u2[j] = s2; cb[j] = c;
}

// ============================================================
// alpha_s/alpha_d per node: wave per node, butterfly reduce
// ============================================================
__global__ __launch_bounds__(256)
void alpha_kernel(const float* __restrict__ h, const float* __restrict__ asrc,
                  const float* __restrict__ adst, float* __restrict__ alpha_s,
                  float* __restrict__ alpha_d, int N)
{
    int node = blockIdx.x * 4 + (threadIdx.x >> 6);
    int lane = threadIdx.x & 63;
    if (node >= N) return;
    float v = h[(size_t)node * 64 + lane];
    float ps = v * asrc[lane];
    float pd = v * adst[lane];
#pragma unroll
    for (int off = 32; off > 0; off >>= 1) {
        ps += __shfl_xor(ps, off);
        pd += __shfl_xor(pd, off);
    }
    if (lane == 0) { alpha_s[node] = ps; alpha_d[node] = pd; }
}

// ============================================================
// CSR build step 1: degree histogram (self-loops included)
// ============================================================
__global__ __launch_bounds__(256)
void count_kernel(const int* __restrict__ ei, int E, int N, int* __restrict__ deg)
{
    int t = blockIdx.x * 256 + threadIdx.x;
    int total = E + N;
    if (t >= total) return;
    int d = (t < E) ? ei[E + t] : (t - E);
    atomicAdd(&deg[d], 1);
}

// ============================================================
// CSR build step 2: exclusive scan (block-level, 2048 items/block)
// ============================================================
__global__ __launch_bounds__(256)
void scan_blk(const int* __restrict__ deg, int* __restrict__ rowptr,
              int* __restrict__ bsums, int N)
{
    __shared__ int sh[256];
    int b = blockIdx.x, t = threadIdx.x;
    int base = b * 2048 + t * 8;
    int v[8]; int s = 0;
#pragma unroll
    for (int j = 0; j < 8; j++) {
        v[j] = (base + j < N) ? deg[base + j] : 0;
        s += v[j];
    }
    sh[t] = s; __syncthreads();
#pragma unroll
    for (int off = 1; off < 256; off <<= 1) {
        int x = (t >= off) ? sh[t - off] : 0;
        __syncthreads();
        sh[t] += x;
        __syncthreads();
    }
    if (t == 255) bsums[b] = sh[255];
    int run = (t > 0) ? sh[t - 1] : 0;   // exclusive prefix within block
#pragma unroll
    for (int j = 0; j < 8; j++) {
        if (base + j < N) rowptr[base + j] = run;
        run += v[j];
    }
}

__global__ void scan_top(int* __restrict__ bsums, int NB)
{
    __shared__ int sh[256];
    int t = threadIdx.x;
    sh[t] = (t < NB) ? bsums[t] : 0;
    __syncthreads();
#pragma unroll
    for (int off = 1; off < 256; off <<= 1) {
        int x = (t >= off) ? sh[t - off] : 0;
        __syncthreads();
        sh[t] += x;
        __syncthreads();
    }
    if (t < NB) bsums[t] = (t > 0) ? sh[t - 1] : 0;
}

__global__ __launch_bounds__(256)
void scan_add(int* __restrict__ rowptr, int* __restrict__ cursor,
              const int* __restrict__ bsums, int N)
{
    int i = blockIdx.x * 256 + threadIdx.x;
    if (i >= N) return;
    int v = rowptr[i] + bsums[i >> 11];
    rowptr[i] = v;
    cursor[i] = v;
}

// ============================================================
// CSR build step 3: scatter (src, exp(leaky_relu(e))) into slots.
// No max-shift: e = aS+aD with aS,aD ~ N(0,~1): exp safe in fp32.
// ============================================================
__global__ __launch_bounds__(256)
void scatter_kernel(const int* __restrict__ ei, int E, int N,
                    const float* __restrict__ alS, const float* __restrict__ alD,
                    int* __restrict__ cursor,
                    int* __restrict__ srcs, float* __restrict__ exv)
{
    int t = blockIdx.x * 256 + threadIdx.x;
    int total = E + N;
    if (t >= total) return;
    int s, d;
    if (t < E) { s = ei[t]; d = ei[E + t]; }
    else       { s = t - E; d = s; }
    float v = alS[s] + alD[d];
    v = v > 0.f ? v : NSLOPE * v;
    float ex = expf(v);
    int pos = atomicAdd(&cursor[d], 1);
    srcs[pos] = s;
    exv[pos] = ex;
}

// ============================================================
// Gather-aggregate: wave per dst node. After scatter, cursor[d]
// == rowptr[d] + deg[d] == segment end. Folds denom, normalize,
// and gat_b -> writes final x3.
// ============================================================
__global__ __launch_bounds__(256)
void aggregate_kernel(const int* __restrict__ rowptr, const int* __restrict__ cursor,
                      const int* __restrict__ srcs, const float* __restrict__ exv,
                      const float* __restrict__ h, const float* __restrict__ gatb,
                      float* __restrict__ x3, int N)
{
    int node = blockIdx.x * 4 + (threadIdx.x >> 6);
    int lane = threadIdx.x & 63;
    if (node >= N) return;
    int start = rowptr[node];
    int end   = cursor[node];
    float accv = 0.f, den = 0.f;
    for (int p = start; p < end; p += 64) {
        int idx = p + lane;
        int ss = 0; float ex = 0.f;
        if (idx < end) { ss = srcs[idx]; ex = exv[idx]; }
        int cnt = end - p; if (cnt > 64) cnt = 64;
        for (int j = 0; j < cnt; j++) {
            int   sj = __shfl(ss, j);
            float ej = __shfl(ex, j);
            den += ej;
            accv += ej * h[(size_t)sj * 64 + lane];
        }
    }
    x3[(size_t)node * 64 + lane] = accv / (den + 1e-16f) + gatb[lane];
}

extern "C" void kernel_launch(void* const* d_in, const int* in_sizes, int n_in,
                              void* d_out, int out_size, void* d_ws, size_t ws_size,
                              hipStream_t stream)
{
    const float* x      = (const float*)d_in[0];
    const int*   ei     = (const int*)d_in[1];
    const float* w1     = (const float*)d_in[2];
    const float* b1     = (const float*)d_in[3];
    const float* w2     = (const float*)d_in[4];
    const float* b2     = (const float*)d_in[5];
    const float* gat_w  = (const float*)d_in[6];
    const float* gat_as = (const float*)d_in[7];
    const float* gat_ad = (const float*)d_in[8];
    const float* gat_b  = (const float*)d_in[9];
    const float* fc1w   = (const float*)d_in[10];
    const float* fc1b   = (const float*)d_in[11];
    const float* fc2w   = (const float*)d_in[12];
    const float* fc2b   = (const float*)d_in[13];
    const float* fc3w   = (const float*)d_in[14];
    const float* fc3b   = (const float*)d_in[15];

    const int N = in_sizes[0] / 130;
    const int E = in_sizes[1] / 2;
    const int total = E + N;
    float* out = (float*)d_out;

    // ---- workspace layout ----
    float* ws = (float*)d_ws;
    size_t off = 0;
    float* h      = ws + off; off += (size_t)N * 64;
    float* x3     = ws + off; off += (size_t)N * 64;
    float* alS    = ws + off; off += (size_t)N;
    float* alD    = ws + off; off += (size_t)N;
    float* u1     = ws + off; off += 512;
    float* u2     = ws + off; off += 512;
    float* cb     = ws + off; off += 512;
    int*   deg    = (int*)(ws + off); off += (size_t)N;
    int*   rowptr = (int*)(ws + off); off += (size_t)N;
    int*   cursor = (int*)(ws + off); off += (size_t)N;
    int*   bsums  = (int*)(ws + off); off += 512;
    int*   srcs   = (int*)(ws + off); off += (size_t)total;
    float* exv    = ws + off;         off += (size_t)total;
    size_t fixed = off;

    // chunked MLP intermediates (512 floats per node-row: 384 + 128)
    size_t wsf = ws_size / sizeof(float);
    size_t avail_rows = (wsf > fixed) ? (wsf - fixed) / 512 : 0;
    size_t CHUNKs = avail_rows & ~(size_t)127;
    if (CHUNKs > (size_t)N) CHUNKs = ((size_t)N + 127) & ~(size_t)127;
    int CHUNK = (CHUNKs < 128) ? 128 : (int)CHUNKs;
    float* h1c = ws + off; off += (size_t)CHUNK * 384;
    float* h2c = ws + off;

    // zero degree histogram only
    hipMemsetAsync(deg, 0, (size_t)N * sizeof(int), stream);

    prep_u<<<3, 128, 0, stream>>>(w1, b1, w2, b2, fc1w, fc1b, u1, u2, cb);

    const int mt128 = (N + 127) / 128;

    // h = x[:,2:] @ gat_w
    gemm_tile<64><<<dim3(mt128, 1), 256, 0, stream>>>(
        x + 2, 130, gat_w, 64, h, 64, N, 128,
        nullptr, 0, nullptr, nullptr, nullptr, 0);

    alpha_kernel<<<(N + 3) / 4, 256, 0, stream>>>(h, gat_as, gat_ad, alS, alD, N);

    // CSR build
    count_kernel<<<(total + 255) / 256, 256, 0, stream>>>(ei, E, N, deg);
    int NB = (N + 2047) / 2048;
    scan_blk<<<NB, 256, 0, stream>>>(deg, rowptr, bsums, N);
    scan_top<<<1, 256, 0, stream>>>(bsums, NB);
    scan_add<<<(N + 255) / 256, 256, 0, stream>>>(rowptr, cursor, bsums, N);
    scatter_kernel<<<(total + 255) / 256, 256, 0, stream>>>(ei, E, N, alS, alD,
                                                            cursor, srcs, exv);

    // aggregate (+normalize +bias) -> x3
    aggregate_kernel<<<(N + 3) / 4, 256, 0, stream>>>(rowptr, cursor, srcs, exv,
                                                      h, gat_b, x3, N);

    // MLP
    for (int start = 0; start < N; start += CHUNK) {
        int mc = N - start; if (mc > CHUNK) mc = CHUNK;
        int mtc = (mc + 127) / 128;
        // fc1: relu(x3 @ fc1_w[128:192,:] + x0*u1 + x1*u2 + cb)
        gemm_tile<128><<<dim3(mtc, 3), 256, 0, stream>>>(
            x3 + (size_t)start * 64, 64, fc1w + (size_t)128 * 384, 384,
            h1c, 384, mc, 64, cb, 1, u1, u2, x + (size_t)start * 130, 130);
        // fc2: relu(h1 @ fc2_w + fc2_b)
        gemm_tile<128><<<dim3(mtc, 1), 256, 0, stream>>>(
            h1c, 384, fc2w, 128, h2c, 128, mc, 384,
            fc2b, 1, nullptr, nullptr, nullptr, 0);
        // fc3: h2 @ fc3_w + fc3_b -> out
        gemm_tile<64><<<dim3(mtc, 1), 256, 0, stream>>>(
            h2c, 128, fc3w, 64, out + (size_t)start * 64, 64, mc, 128,
            fc3b, 0, nullptr, nullptr, nullptr, 0);
    }
}

// Round 3
// 875.057 us; speedup vs baseline: 1.6094x; 1.4224x over previous
//
#include <hip/hip_runtime.h>
#include <math.h>

#define NSLOPE 0.2f

typedef __attribute__((ext_vector_type(8))) short  bf16x8;
typedef __attribute__((ext_vector_type(4))) float  floatx4;

__device__ __forceinline__ unsigned short f2bf(float f) {
    unsigned u = __builtin_bit_cast(unsigned, f);
    u += 0x7fff + ((u >> 16) & 1);          // RNE
    return (unsigned short)(u >> 16);
}
__device__ __forceinline__ float bf2f(unsigned short h) {
    unsigned u = (unsigned)h << 16;
    return __builtin_bit_cast(float, u);
}

// ============================================================
// Split-bf16 MFMA GEMM.  C[M, TNB*16*gridDim.y] = act(A @ B + ...)
// A: fp32 [M x K] (lda), B: pre-split bf16 hi/lo planes in [n][k]
// layout.  No LDS, no barriers: wave = 32 rows x TN*16 cols,
// block = 4 waves = 128 rows.  C = Ahi*Bhi + Ahi*Blo + Alo*Bhi
// (fp32 accum) -> ~3e-5 rel err.
// A-frag: A[m=lane&15][k=quad*8+j]; B-frag: B[n=lane&15][k=quad*8+j];
// D-frag: col=lane&15, row=quad*4+reg   [guide-verified layouts]
// ============================================================
template<int K, int TN>
__global__ __launch_bounds__(256, 2)
void gemm_mfma(const float* __restrict__ A, int lda,
               const unsigned short* __restrict__ Bhi,
               const unsigned short* __restrict__ Blo,
               float* __restrict__ C, int ldc, int M,
               const float* __restrict__ bias, int do_relu,
               const float* __restrict__ u1, const float* __restrict__ u2,
               const float* __restrict__ xrow, int xld)
{
    const int lane = threadIdx.x & 63;
    const int wv   = threadIdx.x >> 6;
    const int l15  = lane & 15;
    const int quad = lane >> 4;
    const int m0   = blockIdx.x * 128 + wv * 32;
    const int col0 = blockIdx.y * (TN * 16);

    floatx4 acc[2][TN];
#pragma unroll
    for (int mt = 0; mt < 2; mt++)
#pragma unroll
        for (int nt = 0; nt < TN; nt++) acc[mt][nt] = (floatx4){0.f, 0.f, 0.f, 0.f};

    int r0 = m0 + l15;       if (r0 >= M) r0 = M - 1;
    int r1 = m0 + 16 + l15;  if (r1 >= M) r1 = M - 1;
    // 8-byte-aligned base (works for lda=130 + offset-2 case too)
    const float* a0 = A + (size_t)r0 * lda + quad * 8;
    const float* a1 = A + (size_t)r1 * lda + quad * 8;

#pragma unroll 4
    for (int kt = 0; kt < K / 32; kt++) {
        const int kb = kt * 32;
        float av[2][8];
        {
            const float2* p0 = (const float2*)(a0 + kb);
            const float2* p1 = (const float2*)(a1 + kb);
#pragma unroll
            for (int j = 0; j < 4; j++) {
                float2 q0 = p0[j], q1 = p1[j];
                av[0][2 * j] = q0.x; av[0][2 * j + 1] = q0.y;
                av[1][2 * j] = q1.x; av[1][2 * j + 1] = q1.y;
            }
        }
        bf16x8 ah[2], al[2];
#pragma unroll
        for (int mt = 0; mt < 2; mt++)
#pragma unroll
            for (int j = 0; j < 8; j++) {
                float v = av[mt][j];
                unsigned short h = f2bf(v);
                ah[mt][j] = (short)h;
                al[mt][j] = (short)f2bf(v - bf2f(h));
            }
#pragma unroll
        for (int nt = 0; nt < TN; nt++) {
            const size_t boff = (size_t)(col0 + nt * 16 + l15) * K + kb + quad * 8;
            bf16x8 bh = *(const bf16x8*)(Bhi + boff);
            bf16x8 bl = *(const bf16x8*)(Blo + boff);
#pragma unroll
            for (int mt = 0; mt < 2; mt++) {
                acc[mt][nt] = __builtin_amdgcn_mfma_f32_16x16x32_bf16(ah[mt], bh, acc[mt][nt], 0, 0, 0);
                acc[mt][nt] = __builtin_amdgcn_mfma_f32_16x16x32_bf16(ah[mt], bl, acc[mt][nt], 0, 0, 0);
                acc[mt][nt] = __builtin_amdgcn_mfma_f32_16x16x32_bf16(al[mt], bh, acc[mt][nt], 0, 0, 0);
            }
        }
    }

    // epilogue: row = m0 + mt*16 + quad*4 + r, col = col0 + nt*16 + l15
#pragma unroll
    for (int mt = 0; mt < 2; mt++) {
#pragma unroll
        for (int r = 0; r < 4; r++) {
            int row = m0 + mt * 16 + quad * 4 + r;
            if (row >= M) continue;
            float x0 = 0.f, x1 = 0.f;
            if (u1) {
                x0 = xrow[(size_t)row * xld];
                x1 = xrow[(size_t)row * xld + 1];
            }
#pragma unroll
            for (int nt = 0; nt < TN; nt++) {
                int col = col0 + nt * 16 + l15;
                float v = acc[mt][nt][r];
                if (bias) v += bias[col];
                if (u1) v += x0 * u1[col] + x1 * u2[col];
                if (do_relu) v = v > 0.f ? v : 0.f;
                C[(size_t)row * ldc + col] = v;
            }
        }
    }
}

// ============================================================
// Pre-split weights: W fp32 [K x Nc] row-major (ldw) ->
// hi/lo bf16 planes in [n][k] layout (idx = n*K + k)
// ============================================================
__global__ void split_w(const float* __restrict__ W, int K, int Nc, int ldw,
                        unsigned short* __restrict__ hi, unsigned short* __restrict__ lo)
{
    int idx = blockIdx.x * 256 + threadIdx.x;
    if (idx >= K * Nc) return;
    int n = idx / K, k = idx - n * K;
    float v = W[(size_t)k * ldw + n];
    unsigned short h = f2bf(v);
    hi[idx] = h;
    lo[idx] = f2bf(v - bf2f(h));
}

// ============================================================
// rank-1 folds of x1/x2 paths into fc1
// ============================================================
__global__ void prep_u(const float* __restrict__ w1, const float* __restrict__ b1,
                       const float* __restrict__ w2, const float* __restrict__ b2,
                       const float* __restrict__ fc1w, const float* __restrict__ fc1b,
                       float* __restrict__ u1, float* __restrict__ u2, float* __restrict__ cb)
{
    int j = threadIdx.x + blockIdx.x * blockDim.x;
    if (j >= 384) return;
    float s1 = 0.f, s2 = 0.f, c = fc1b[j];
    for (int k = 0; k < 64; k++) {
        float wv = fc1w[k * 384 + j];
        s1 += w1[k] * wv; c += b1[k] * wv;
    }
    for (int k = 0; k < 64; k++) {
        float wv = fc1w[(64 + k) * 384 + j];
        s2 += w2[k] * wv; c += b2[k] * wv;
    }
    u1[j] = s1; u2[j] = s2; cb[j] = c;
}

// ============================================================
// alpha_s/alpha_d per node: wave per node, butterfly reduce
// ============================================================
__global__ __launch_bounds__(256)
void alpha_kernel(const float* __restrict__ h, const float* __restrict__ asrc,
                  const float* __restrict__ adst, float* __restrict__ alpha_s,
                  float* __restrict__ alpha_d, int N)
{
    int node = blockIdx.x * 4 + (threadIdx.x >> 6);
    int lane = threadIdx.x & 63;
    if (node >= N) return;
    float v = h[(size_t)node * 64 + lane];
    float ps = v * asrc[lane];
    float pd = v * adst[lane];
#pragma unroll
    for (int off = 32; off > 0; off >>= 1) {
        ps += __shfl_xor(ps, off);
        pd += __shfl_xor(pd, off);
    }
    if (lane == 0) { alpha_s[node] = ps; alpha_d[node] = pd; }
}

// ============================================================
// CSR build step 1: degree histogram (self-loops included)
// ============================================================
__global__ __launch_bounds__(256)
void count_kernel(const int* __restrict__ ei, int E, int N, int* __restrict__ deg)
{
    int t = blockIdx.x * 256 + threadIdx.x;
    int total = E + N;
    if (t >= total) return;
    int d = (t < E) ? ei[E + t] : (t - E);
    atomicAdd(&deg[d], 1);
}

// ============================================================
// CSR build step 2: exclusive scan (2048 items/block)
// ============================================================
__global__ __launch_bounds__(256)
void scan_blk(const int* __restrict__ deg, int* __restrict__ rowptr,
              int* __restrict__ bsums, int N)
{
    __shared__ int sh[256];
    int b = blockIdx.x, t = threadIdx.x;
    int base = b * 2048 + t * 8;
    int v[8]; int s = 0;
#pragma unroll
    for (int j = 0; j < 8; j++) {
        v[j] = (base + j < N) ? deg[base + j] : 0;
        s += v[j];
    }
    sh[t] = s; __syncthreads();
#pragma unroll
    for (int off = 1; off < 256; off <<= 1) {
        int x = (t >= off) ? sh[t - off] : 0;
        __syncthreads();
        sh[t] += x;
        __syncthreads();
    }
    if (t == 255) bsums[b] = sh[255];
    int run = (t > 0) ? sh[t - 1] : 0;
#pragma unroll
    for (int j = 0; j < 8; j++) {
        if (base + j < N) rowptr[base + j] = run;
        run += v[j];
    }
}

__global__ void scan_top(int* __restrict__ bsums, int NB)
{
    __shared__ int sh[256];
    int t = threadIdx.x;
    sh[t] = (t < NB) ? bsums[t] : 0;
    __syncthreads();
#pragma unroll
    for (int off = 1; off < 256; off <<= 1) {
        int x = (t >= off) ? sh[t - off] : 0;
        __syncthreads();
        sh[t] += x;
        __syncthreads();
    }
    if (t < NB) bsums[t] = (t > 0) ? sh[t - 1] : 0;
}

__global__ __launch_bounds__(256)
void scan_add(int* __restrict__ rowptr, int* __restrict__ cursor,
              const int* __restrict__ bsums, int N)
{
    int i = blockIdx.x * 256 + threadIdx.x;
    if (i >= N) return;
    int v = rowptr[i] + bsums[i >> 11];
    rowptr[i] = v;
    cursor[i] = v;
}

// ============================================================
// CSR build step 3: scatter (src, exp(leaky_relu(e))) into slots
// ============================================================
__global__ __launch_bounds__(256)
void scatter_kernel(const int* __restrict__ ei, int E, int N,
                    const float* __restrict__ alS, const float* __restrict__ alD,
                    int* __restrict__ cursor,
                    int* __restrict__ srcs, float* __restrict__ exv)
{
    int t = blockIdx.x * 256 + threadIdx.x;
    int total = E + N;
    if (t >= total) return;
    int s, d;
    if (t < E) { s = ei[t]; d = ei[E + t]; }
    else       { s = t - E; d = s; }
    float v = alS[s] + alD[d];
    v = v > 0.f ? v : NSLOPE * v;
    float ex = expf(v);
    int pos = atomicAdd(&cursor[d], 1);
    srcs[pos] = s;
    exv[pos] = ex;
}

// ============================================================
// Gather-aggregate + normalize + bias -> x3
// ============================================================
__global__ __launch_bounds__(256)
void aggregate_kernel(const int* __restrict__ rowptr, const int* __restrict__ cursor,
                      const int* __restrict__ srcs, const float* __restrict__ exv,
                      const float* __restrict__ h, const float* __restrict__ gatb,
                      float* __restrict__ x3, int N)
{
    int node = blockIdx.x * 4 + (threadIdx.x >> 6);
    int lane = threadIdx.x & 63;
    if (node >= N) return;
    int start = rowptr[node];
    int end   = cursor[node];
    float accv = 0.f, den = 0.f;
    for (int p = start; p < end; p += 64) {
        int idx = p + lane;
        int ss = 0; float ex = 0.f;
        if (idx < end) { ss = srcs[idx]; ex = exv[idx]; }
        int cnt = end - p; if (cnt > 64) cnt = 64;
        for (int j = 0; j < cnt; j++) {
            int   sj = __shfl(ss, j);
            float ej = __shfl(ex, j);
            den += ej;
            accv += ej * h[(size_t)sj * 64 + lane];
        }
    }
    x3[(size_t)node * 64 + lane] = accv / (den + 1e-16f) + gatb[lane];
}

extern "C" void kernel_launch(void* const* d_in, const int* in_sizes, int n_in,
                              void* d_out, int out_size, void* d_ws, size_t ws_size,
                              hipStream_t stream)
{
    const float* x      = (const float*)d_in[0];
    const int*   ei     = (const int*)d_in[1];
    const float* w1     = (const float*)d_in[2];
    const float* b1     = (const float*)d_in[3];
    const float* w2     = (const float*)d_in[4];
    const float* b2     = (const float*)d_in[5];
    const float* gat_w  = (const float*)d_in[6];
    const float* gat_as = (const float*)d_in[7];
    const float* gat_ad = (const float*)d_in[8];
    const float* gat_b  = (const float*)d_in[9];
    const float* fc1w   = (const float*)d_in[10];
    const float* fc1b   = (const float*)d_in[11];
    const float* fc2w   = (const float*)d_in[12];
    const float* fc2b   = (const float*)d_in[13];
    const float* fc3w   = (const float*)d_in[14];
    const float* fc3b   = (const float*)d_in[15];

    const int N = in_sizes[0] / 130;
    const int E = in_sizes[1] / 2;
    const int total = E + N;
    float* out = (float*)d_out;

    // ---- workspace layout ----
    float* ws = (float*)d_ws;
    size_t off = 0;
    float* h      = ws + off; off += (size_t)N * 64;
    float* x3     = ws + off; off += (size_t)N * 64;
    float* alS    = ws + off; off += (size_t)N;
    float* alD    = ws + off; off += (size_t)N;
    float* u1     = ws + off; off += 512;
    float* u2     = ws + off; off += 512;
    float* cb     = ws + off; off += 512;
    int*   deg    = (int*)(ws + off); off += (size_t)N;
    int*   rowptr = (int*)(ws + off); off += (size_t)N;
    int*   cursor = (int*)(ws + off); off += (size_t)N;
    int*   bsums  = (int*)(ws + off); off += 512;
    int*   srcs   = (int*)(ws + off); off += (size_t)total;
    float* exv    = ws + off;         off += (size_t)total;
    // split-weight planes (bf16 hi/lo, [n][k] layout)
    unsigned short* gatHi = (unsigned short*)(ws + off); off += 4096;   // 64*128
    unsigned short* gatLo = (unsigned short*)(ws + off); off += 4096;
    unsigned short* f1Hi  = (unsigned short*)(ws + off); off += 12288;  // 384*64
    unsigned short* f1Lo  = (unsigned short*)(ws + off); off += 12288;
    unsigned short* f2Hi  = (unsigned short*)(ws + off); off += 24576;  // 128*384
    unsigned short* f2Lo  = (unsigned short*)(ws + off); off += 24576;
    unsigned short* f3Hi  = (unsigned short*)(ws + off); off += 4096;   // 64*128
    unsigned short* f3Lo  = (unsigned short*)(ws + off); off += 4096;
    size_t fixed = off;

    // chunked MLP intermediates (512 floats per node-row: 384 + 128)
    size_t wsf = ws_size / sizeof(float);
    size_t avail_rows = (wsf > fixed) ? (wsf - fixed) / 512 : 0;
    size_t CHUNKs = avail_rows & ~(size_t)127;
    if (CHUNKs > (size_t)N) CHUNKs = ((size_t)N + 127) & ~(size_t)127;
    int CHUNK = (CHUNKs < 128) ? 128 : (int)CHUNKs;
    float* h1c = ws + off; off += (size_t)CHUNK * 384;
    float* h2c = ws + off;

    hipMemsetAsync(deg, 0, (size_t)N * sizeof(int), stream);

    prep_u<<<3, 128, 0, stream>>>(w1, b1, w2, b2, fc1w, fc1b, u1, u2, cb);
    split_w<<<(128 * 64 + 255) / 256, 256, 0, stream>>>(gat_w, 128, 64, 64, gatHi, gatLo);
    split_w<<<(64 * 384 + 255) / 256, 256, 0, stream>>>(fc1w + (size_t)128 * 384, 64, 384, 384, f1Hi, f1Lo);
    split_w<<<(384 * 128 + 255) / 256, 256, 0, stream>>>(fc2w, 384, 128, 128, f2Hi, f2Lo);
    split_w<<<(128 * 64 + 255) / 256, 256, 0, stream>>>(fc3w, 128, 64, 64, f3Hi, f3Lo);

    const int mt128 = (N + 127) / 128;

    // h = x[:,2:] @ gat_w   (K=128, N=64)
    gemm_mfma<128, 4><<<dim3(mt128, 1), 256, 0, stream>>>(
        x + 2, 130, gatHi, gatLo, h, 64, N,
        nullptr, 0, nullptr, nullptr, nullptr, 0);

    alpha_kernel<<<(N + 3) / 4, 256, 0, stream>>>(h, gat_as, gat_ad, alS, alD, N);

    // CSR build
    count_kernel<<<(total + 255) / 256, 256, 0, stream>>>(ei, E, N, deg);
    int NB = (N + 2047) / 2048;
    scan_blk<<<NB, 256, 0, stream>>>(deg, rowptr, bsums, N);
    scan_top<<<1, 256, 0, stream>>>(bsums, NB);
    scan_add<<<(N + 255) / 256, 256, 0, stream>>>(rowptr, cursor, bsums, N);
    scatter_kernel<<<(total + 255) / 256, 256, 0, stream>>>(ei, E, N, alS, alD,
                                                            cursor, srcs, exv);

    aggregate_kernel<<<(N + 3) / 4, 256, 0, stream>>>(rowptr, cursor, srcs, exv,
                                                      h, gat_b, x3, N);

    // MLP
    for (int start = 0; start < N; start += CHUNK) {
        int mc = N - start; if (mc > CHUNK) mc = CHUNK;
        int mtc = (mc + 127) / 128;
        // fc1: relu(x3 @ fc1_w[128:192,:] + x0*u1 + x1*u2 + cb)  (K=64, N=384)
        gemm_mfma<64, 8><<<dim3(mtc, 3), 256, 0, stream>>>(
            x3 + (size_t)start * 64, 64, f1Hi, f1Lo,
            h1c, 384, mc, cb, 1, u1, u2, x + (size_t)start * 130, 130);
        // fc2: relu(h1 @ fc2_w + fc2_b)  (K=384, N=128)
        gemm_mfma<384, 8><<<dim3(mtc, 1), 256, 0, stream>>>(
            h1c, 384, f2Hi, f2Lo, h2c, 128, mc,
            fc2b, 1, nullptr, nullptr, nullptr, 0);
        // fc3: h2 @ fc3_w + fc3_b  (K=128, N=64)
        gemm_mfma<128, 4><<<dim3(mtc, 1), 256, 0, stream>>>(
            h2c, 128, f3Hi, f3Lo, out + (size_t)start * 64, 64, mc,
            fc3b, 0, nullptr, nullptr, nullptr, 0);
    }
}

// Round 4
// 571.222 us; speedup vs baseline: 2.4655x; 1.5319x over previous
//
#include <hip/hip_runtime.h>
#include <math.h>

#define NSLOPE 0.2f

typedef __attribute__((ext_vector_type(8))) short  bf16x8;
typedef __attribute__((ext_vector_type(4))) float  floatx4;

__device__ __forceinline__ unsigned short f2bf(float f) {
    unsigned u = __builtin_bit_cast(unsigned, f);
    u += 0x7fff + ((u >> 16) & 1);          // RNE
    return (unsigned short)(u >> 16);
}
__device__ __forceinline__ float bf2f(unsigned short h) {
    unsigned u = (unsigned)h << 16;
    return __builtin_bit_cast(float, u);
}

// split 8 fp32 -> hi/lo bf16x8
__device__ __forceinline__ void split8(const float* v, bf16x8& hi, bf16x8& lo) {
#pragma unroll
    for (int j = 0; j < 8; j++) {
        unsigned short h = f2bf(v[j]);
        hi[j] = (short)h;
        lo[j] = (short)f2bf(v[j] - bf2f(h));
    }
}

// unpack 8 interleaved u32 ((lo<<16)|hi) -> hi/lo bf16x8
__device__ __forceinline__ void unpack8(uint4 a, uint4 b, bf16x8& hi, bf16x8& lo) {
    unsigned w[8] = {a.x, a.y, a.z, a.w, b.x, b.y, b.z, b.w};
#pragma unroll
    for (int j = 0; j < 8; j++) {
        hi[j] = (short)(w[j] & 0xFFFFu);
        lo[j] = (short)(w[j] >> 16);
    }
}

// ============================================================
// h-projection + alpha fold:
//   h = x[:,2:] @ gat_w  (K=128, Ncols=64), split-bf16 MFMA
//   alpha_s[n] = h[n,:]·a_src ; alpha_d[n] = h[n,:]·a_dst
// wave = 32 rows, block = 128 rows. No LDS.
// A-frag: A[m=l15][k=quad*8+j]; B-frag: B[n=l15][k=quad*8+j]
// D-frag: col=l15, row=quad*4+reg
// ============================================================
__global__ __launch_bounds__(256, 2)
void hproj_kernel(const float* __restrict__ x,          // [M x 130], use cols 2..129
                  const unsigned short* __restrict__ Bhi,
                  const unsigned short* __restrict__ Blo,
                  const float* __restrict__ asrc, const float* __restrict__ adst,
                  float* __restrict__ h, float* __restrict__ alS,
                  float* __restrict__ alD, int M)
{
    const int lane = threadIdx.x & 63;
    const int wv   = threadIdx.x >> 6;
    const int l15  = lane & 15;
    const int quad = lane >> 4;
    const int m0   = blockIdx.x * 128 + wv * 32;

    floatx4 acc[2][4];
#pragma unroll
    for (int mt = 0; mt < 2; mt++)
#pragma unroll
        for (int nt = 0; nt < 4; nt++) acc[mt][nt] = (floatx4){0.f, 0.f, 0.f, 0.f};

    int r0 = m0 + l15;      if (r0 >= M) r0 = M - 1;
    int r1 = m0 + 16 + l15; if (r1 >= M) r1 = M - 1;
    const float* a0 = x + (size_t)r0 * 130 + 2 + quad * 8;
    const float* a1 = x + (size_t)r1 * 130 + 2 + quad * 8;

#pragma unroll
    for (int kt = 0; kt < 4; kt++) {
        const int kb = kt * 32;
        float av[2][8];
#pragma unroll
        for (int j = 0; j < 4; j++) {
            float2 q0 = *(const float2*)(a0 + kb + 2 * j);
            float2 q1 = *(const float2*)(a1 + kb + 2 * j);
            av[0][2 * j] = q0.x; av[0][2 * j + 1] = q0.y;
            av[1][2 * j] = q1.x; av[1][2 * j + 1] = q1.y;
        }
        bf16x8 ah[2], al[2];
        split8(av[0], ah[0], al[0]);
        split8(av[1], ah[1], al[1]);
#pragma unroll
        for (int nt = 0; nt < 4; nt++) {
            const size_t boff = (size_t)(nt * 16 + l15) * 128 + kb + quad * 8;
            bf16x8 bh = *(const bf16x8*)(Bhi + boff);
            bf16x8 bl = *(const bf16x8*)(Blo + boff);
#pragma unroll
            for (int mt = 0; mt < 2; mt++) {
                acc[mt][nt] = __builtin_amdgcn_mfma_f32_16x16x32_bf16(ah[mt], bh, acc[mt][nt], 0, 0, 0);
                acc[mt][nt] = __builtin_amdgcn_mfma_f32_16x16x32_bf16(ah[mt], bl, acc[mt][nt], 0, 0, 0);
                acc[mt][nt] = __builtin_amdgcn_mfma_f32_16x16x32_bf16(al[mt], bh, acc[mt][nt], 0, 0, 0);
            }
        }
    }

    float as4[4], ad4[4];
#pragma unroll
    for (int nt = 0; nt < 4; nt++) {
        as4[nt] = asrc[nt * 16 + l15];
        ad4[nt] = adst[nt * 16 + l15];
    }

    float ps[2][4], pd[2][4];
#pragma unroll
    for (int mt = 0; mt < 2; mt++) {
#pragma unroll
        for (int r = 0; r < 4; r++) {
            int row = m0 + mt * 16 + quad * 4 + r;
            float s = 0.f, d = 0.f;
#pragma unroll
            for (int nt = 0; nt < 4; nt++) {
                float v = acc[mt][nt][r];
                s += v * as4[nt];
                d += v * ad4[nt];
                if (row < M) h[(size_t)row * 64 + nt * 16 + l15] = v;
            }
            ps[mt][r] = s; pd[mt][r] = d;
        }
    }
    // reduce over the 16 l15 lanes (xor of bits 0..3 stays within quad)
#pragma unroll
    for (int mt = 0; mt < 2; mt++)
#pragma unroll
        for (int r = 0; r < 4; r++) {
#pragma unroll
            for (int msk = 1; msk < 16; msk <<= 1) {
                ps[mt][r] += __shfl_xor(ps[mt][r], msk);
                pd[mt][r] += __shfl_xor(pd[mt][r], msk);
            }
        }
    if (l15 == 0) {
#pragma unroll
        for (int mt = 0; mt < 2; mt++)
#pragma unroll
            for (int r = 0; r < 4; r++) {
                int row = m0 + mt * 16 + quad * 4 + r;
                if (row < M) { alS[row] = ps[mt][r]; alD[row] = pd[mt][r]; }
            }
    }
}

// ============================================================
// Fused MLP: out = (relu(relu(x3@W1 + rank1 + cb) @ W2 + b2)) @ W3 + b3
// Block = 32 rows (M = 3125*32 exactly), 4 waves, 256 threads.
// h1 (32x384) and then h2 (32x128) live in ONE LDS buffer as
// hi/lo-interleaved u32; pads 388/132 give only 2-way bank alias.
// ============================================================
__global__ __launch_bounds__(256, 2)
void fused_mlp(const float* __restrict__ x3,
               const float* __restrict__ x,            // [M x 130] for rank-1 cols
               const unsigned short* __restrict__ f1Hi, const unsigned short* __restrict__ f1Lo,
               const unsigned short* __restrict__ f2Hi, const unsigned short* __restrict__ f2Lo,
               const unsigned short* __restrict__ f3Hi, const unsigned short* __restrict__ f3Lo,
               const float* __restrict__ cb, const float* __restrict__ u1,
               const float* __restrict__ u2, const float* __restrict__ fc2b,
               const float* __restrict__ fc3b,
               float* __restrict__ out, int M)
{
    __shared__ unsigned int hbuf[32 * 388];   // 49.6 KB; reused for h2 (stride 132)
    const int lane = threadIdx.x & 63;
    const int wv   = threadIdx.x >> 6;
    const int l15  = lane & 15;
    const int quad = lane >> 4;
    const int m0   = blockIdx.x * 32;

    // ---- fc1: A-frags from x3 (K=64) ----
    bf16x8 ah[2][2], al[2][2];
    {
        int r0 = m0 + l15;      if (r0 >= M) r0 = M - 1;
        int r1 = m0 + 16 + l15; if (r1 >= M) r1 = M - 1;
        const float* a0 = x3 + (size_t)r0 * 64 + quad * 8;
        const float* a1 = x3 + (size_t)r1 * 64 + quad * 8;
#pragma unroll
        for (int kt = 0; kt < 2; kt++) {
            float av[2][8];
#pragma unroll
            for (int j = 0; j < 4; j++) {
                float2 q0 = *(const float2*)(a0 + kt * 32 + 2 * j);
                float2 q1 = *(const float2*)(a1 + kt * 32 + 2 * j);
                av[0][2 * j] = q0.x; av[0][2 * j + 1] = q0.y;
                av[1][2 * j] = q1.x; av[1][2 * j + 1] = q1.y;
            }
            split8(av[0], ah[0][kt], al[0][kt]);
            split8(av[1], ah[1][kt], al[1][kt]);
        }
    }

    // ---- fc1 MFMAs: wave covers 96 cols (6 n-tiles) ----
    const int colw1 = wv * 96;
    floatx4 acc1[2][6];
#pragma unroll
    for (int mt = 0; mt < 2; mt++)
#pragma unroll
        for (int nt = 0; nt < 6; nt++) acc1[mt][nt] = (floatx4){0.f, 0.f, 0.f, 0.f};
#pragma unroll
    for (int nt = 0; nt < 6; nt++) {
        const size_t cb0 = (size_t)(colw1 + nt * 16 + l15) * 64 + quad * 8;
#pragma unroll
        for (int kt = 0; kt < 2; kt++) {
            bf16x8 bh = *(const bf16x8*)(f1Hi + cb0 + kt * 32);
            bf16x8 bl = *(const bf16x8*)(f1Lo + cb0 + kt * 32);
#pragma unroll
            for (int mt = 0; mt < 2; mt++) {
                acc1[mt][nt] = __builtin_amdgcn_mfma_f32_16x16x32_bf16(ah[mt][kt], bh, acc1[mt][nt], 0, 0, 0);
                acc1[mt][nt] = __builtin_amdgcn_mfma_f32_16x16x32_bf16(ah[mt][kt], bl, acc1[mt][nt], 0, 0, 0);
                acc1[mt][nt] = __builtin_amdgcn_mfma_f32_16x16x32_bf16(al[mt][kt], bh, acc1[mt][nt], 0, 0, 0);
            }
        }
    }

    // ---- fc1 epilogue -> h1 in LDS (interleaved hi|lo<<16), stride 388 ----
#pragma unroll
    for (int mt = 0; mt < 2; mt++) {
#pragma unroll
        for (int r = 0; r < 4; r++) {
            int row = m0 + mt * 16 + quad * 4 + r;
            int rl  = mt * 16 + quad * 4 + r;
            float2 xv = {0.f, 0.f};
            if (row < M) xv = *(const float2*)(x + (size_t)row * 130);
#pragma unroll
            for (int nt = 0; nt < 6; nt++) {
                int col = colw1 + nt * 16 + l15;
                float v = acc1[mt][nt][r] + cb[col] + xv.x * u1[col] + xv.y * u2[col];
                v = v > 0.f ? v : 0.f;
                unsigned short hi = f2bf(v);
                unsigned short lo = f2bf(v - bf2f(hi));
                hbuf[rl * 388 + col] = (unsigned)hi | ((unsigned)lo << 16);
            }
        }
    }
    __syncthreads();

    // ---- fc2: K=384 from LDS h1; wave covers 32 cols (2 n-tiles) ----
    floatx4 acc2[2][2];
#pragma unroll
    for (int mt = 0; mt < 2; mt++)
#pragma unroll
        for (int nt = 0; nt < 2; nt++) acc2[mt][nt] = (floatx4){0.f, 0.f, 0.f, 0.f};
#pragma unroll 4
    for (int kt = 0; kt < 12; kt++) {
        bf16x8 a2h[2], a2l[2];
#pragma unroll
        for (int mt = 0; mt < 2; mt++) {
            int base = (mt * 16 + l15) * 388 + kt * 32 + quad * 8;
            uint4 wa = *(const uint4*)&hbuf[base];
            uint4 wb = *(const uint4*)&hbuf[base + 4];
            unpack8(wa, wb, a2h[mt], a2l[mt]);
        }
#pragma unroll
        for (int nt = 0; nt < 2; nt++) {
            const size_t boff = (size_t)(wv * 32 + nt * 16 + l15) * 384 + kt * 32 + quad * 8;
            bf16x8 bh = *(const bf16x8*)(f2Hi + boff);
            bf16x8 bl = *(const bf16x8*)(f2Lo + boff);
#pragma unroll
            for (int mt = 0; mt < 2; mt++) {
                acc2[mt][nt] = __builtin_amdgcn_mfma_f32_16x16x32_bf16(a2h[mt], bh, acc2[mt][nt], 0, 0, 0);
                acc2[mt][nt] = __builtin_amdgcn_mfma_f32_16x16x32_bf16(a2h[mt], bl, acc2[mt][nt], 0, 0, 0);
                acc2[mt][nt] = __builtin_amdgcn_mfma_f32_16x16x32_bf16(a2l[mt], bh, acc2[mt][nt], 0, 0, 0);
            }
        }
    }
    __syncthreads();   // all h1 reads done before overwrite

    // ---- fc2 epilogue -> h2 in same LDS buffer, stride 132 ----
#pragma unroll
    for (int mt = 0; mt < 2; mt++) {
#pragma unroll
        for (int r = 0; r < 4; r++) {
            int rl = mt * 16 + quad * 4 + r;
#pragma unroll
            for (int nt = 0; nt < 2; nt++) {
                int col = wv * 32 + nt * 16 + l15;
                float v = acc2[mt][nt][r] + fc2b[col];
                v = v > 0.f ? v : 0.f;
                unsigned short hi = f2bf(v);
                unsigned short lo = f2bf(v - bf2f(hi));
                hbuf[rl * 132 + col] = (unsigned)hi | ((unsigned)lo << 16);
            }
        }
    }
    __syncthreads();

    // ---- fc3: K=128 from LDS h2; wave covers 16 cols (1 n-tile) ----
    floatx4 acc3[2];
    acc3[0] = (floatx4){0.f, 0.f, 0.f, 0.f};
    acc3[1] = (floatx4){0.f, 0.f, 0.f, 0.f};
#pragma unroll
    for (int kt = 0; kt < 4; kt++) {
        bf16x8 a3h[2], a3l[2];
#pragma unroll
        for (int mt = 0; mt < 2; mt++) {
            int base = (mt * 16 + l15) * 132 + kt * 32 + quad * 8;
            uint4 wa = *(const uint4*)&hbuf[base];
            uint4 wb = *(const uint4*)&hbuf[base + 4];
            unpack8(wa, wb, a3h[mt], a3l[mt]);
        }
        const size_t boff = (size_t)(wv * 16 + l15) * 128 + kt * 32 + quad * 8;
        bf16x8 bh = *(const bf16x8*)(f3Hi + boff);
        bf16x8 bl = *(const bf16x8*)(f3Lo + boff);
#pragma unroll
        for (int mt = 0; mt < 2; mt++) {
            acc3[mt] = __builtin_amdgcn_mfma_f32_16x16x32_bf16(a3h[mt], bh, acc3[mt], 0, 0, 0);
            acc3[mt] = __builtin_amdgcn_mfma_f32_16x16x32_bf16(a3h[mt], bl, acc3[mt], 0, 0, 0);
            acc3[mt] = __builtin_amdgcn_mfma_f32_16x16x32_bf16(a3l[mt], bh, acc3[mt], 0, 0, 0);
        }
    }
    {
        int col = wv * 16 + l15;
        float bv = fc3b[col];
#pragma unroll
        for (int mt = 0; mt < 2; mt++)
#pragma unroll
            for (int r = 0; r < 4; r++) {
                int row = m0 + mt * 16 + quad * 4 + r;
                if (row < M) out[(size_t)row * 64 + col] = acc3[mt][r] + bv;
            }
    }
}

// ============================================================
// Pre-split weights: W fp32 [K x Nc] row-major (ldw) ->
// hi/lo bf16 planes in [n][k] layout (idx = n*K + k)
// ============================================================
__global__ void split_w(const float* __restrict__ W, int K, int Nc, int ldw,
                        unsigned short* __restrict__ hi, unsigned short* __restrict__ lo)
{
    int idx = blockIdx.x * 256 + threadIdx.x;
    if (idx >= K * Nc) return;
    int n = idx / K, k = idx - n * K;
    float v = W[(size_t)k * ldw + n];
    unsigned short h = f2bf(v);
    hi[idx] = h;
    lo[idx] = f2bf(v - bf2f(h));
}

// ============================================================
// rank-1 folds of x1/x2 paths into fc1
// ============================================================
__global__ void prep_u(const float* __restrict__ w1, const float* __restrict__ b1,
                       const float* __restrict__ w2, const float* __restrict__ b2,
                       const float* __restrict__ fc1w, const float* __restrict__ fc1b,
                       float* __restrict__ u1, float* __restrict__ u2, float* __restrict__ cb)
{
    int j = threadIdx.x + blockIdx.x * blockDim.x;
    if (j >= 384) return;
    float s1 = 0.f, s2 = 0.f, c = fc1b[j];
    for (int k = 0; k < 64; k++) {
        float wv = fc1w[k * 384 + j];
        s1 += w1[k] * wv; c += b1[k] * wv;
    }
    for (int k = 0; k < 64; k++) {
        float wv = fc1w[(64 + k) * 384 + j];
        s2 += w2[k] * wv; c += b2[k] * wv;
    }
    u1[j] = s1; u2[j] = s2; cb[j] = c;
}

// ============================================================
// CSR build
// ============================================================
__global__ __launch_bounds__(256)
void count_kernel(const int* __restrict__ ei, int E, int N, int* __restrict__ deg)
{
    int t = blockIdx.x * 256 + threadIdx.x;
    int total = E + N;
    if (t >= total) return;
    int d = (t < E) ? ei[E + t] : (t - E);
    atomicAdd(&deg[d], 1);
}

__global__ __launch_bounds__(256)
void scan_blk(const int* __restrict__ deg, int* __restrict__ rowptr,
              int* __restrict__ bsums, int N)
{
    __shared__ int sh[256];
    int b = blockIdx.x, t = threadIdx.x;
    int base = b * 2048 + t * 8;
    int v[8]; int s = 0;
#pragma unroll
    for (int j = 0; j < 8; j++) {
        v[j] = (base + j < N) ? deg[base + j] : 0;
        s += v[j];
    }
    sh[t] = s; __syncthreads();
#pragma unroll
    for (int off = 1; off < 256; off <<= 1) {
        int x = (t >= off) ? sh[t - off] : 0;
        __syncthreads();
        sh[t] += x;
        __syncthreads();
    }
    if (t == 255) bsums[b] = sh[255];
    int run = (t > 0) ? sh[t - 1] : 0;
#pragma unroll
    for (int j = 0; j < 8; j++) {
        if (base + j < N) rowptr[base + j] = run;
        run += v[j];
    }
}

__global__ void scan_top(int* __restrict__ bsums, int NB)
{
    __shared__ int sh[256];
    int t = threadIdx.x;
    sh[t] = (t < NB) ? bsums[t] : 0;
    __syncthreads();
#pragma unroll
    for (int off = 1; off < 256; off <<= 1) {
        int x = (t >= off) ? sh[t - off] : 0;
        __syncthreads();
        sh[t] += x;
        __syncthreads();
    }
    if (t < NB) bsums[t] = (t > 0) ? sh[t - 1] : 0;
}

__global__ __launch_bounds__(256)
void scan_add(int* __restrict__ rowptr, int* __restrict__ cursor,
              const int* __restrict__ bsums, int N)
{
    int i = blockIdx.x * 256 + threadIdx.x;
    if (i >= N) return;
    int v = rowptr[i] + bsums[i >> 11];
    rowptr[i] = v;
    cursor[i] = v;
}

__global__ __launch_bounds__(256)
void scatter_kernel(const int* __restrict__ ei, int E, int N,
                    const float* __restrict__ alS, const float* __restrict__ alD,
                    int* __restrict__ cursor,
                    int* __restrict__ srcs, float* __restrict__ exv)
{
    int t = blockIdx.x * 256 + threadIdx.x;
    int total = E + N;
    if (t >= total) return;
    int s, d;
    if (t < E) { s = ei[t]; d = ei[E + t]; }
    else       { s = t - E; d = s; }
    float v = alS[s] + alD[d];
    v = v > 0.f ? v : NSLOPE * v;
    float ex = expf(v);
    int pos = atomicAdd(&cursor[d], 1);
    srcs[pos] = s;
    exv[pos] = ex;
}

// ============================================================
// Gather-aggregate + normalize + bias -> x3
// ============================================================
__global__ __launch_bounds__(256)
void aggregate_kernel(const int* __restrict__ rowptr, const int* __restrict__ cursor,
                      const int* __restrict__ srcs, const float* __restrict__ exv,
                      const float* __restrict__ h, const float* __restrict__ gatb,
                      float* __restrict__ x3, int N)
{
    int node = blockIdx.x * 4 + (threadIdx.x >> 6);
    int lane = threadIdx.x & 63;
    if (node >= N) return;
    int start = rowptr[node];
    int end   = cursor[node];
    float accv = 0.f, den = 0.f;
    for (int p = start; p < end; p += 64) {
        int idx = p + lane;
        int ss = 0; float ex = 0.f;
        if (idx < end) { ss = srcs[idx]; ex = exv[idx]; }
        int cnt = end - p; if (cnt > 64) cnt = 64;
        for (int j = 0; j < cnt; j++) {
            int   sj = __shfl(ss, j);
            float ej = __shfl(ex, j);
            den += ej;
            accv += ej * h[(size_t)sj * 64 + lane];
        }
    }
    x3[(size_t)node * 64 + lane] = accv / (den + 1e-16f) + gatb[lane];
}

extern "C" void kernel_launch(void* const* d_in, const int* in_sizes, int n_in,
                              void* d_out, int out_size, void* d_ws, size_t ws_size,
                              hipStream_t stream)
{
    const float* x      = (const float*)d_in[0];
    const int*   ei     = (const int*)d_in[1];
    const float* w1     = (const float*)d_in[2];
    const float* b1     = (const float*)d_in[3];
    const float* w2     = (const float*)d_in[4];
    const float* b2     = (const float*)d_in[5];
    const float* gat_w  = (const float*)d_in[6];
    const float* gat_as = (const float*)d_in[7];
    const float* gat_ad = (const float*)d_in[8];
    const float* gat_b  = (const float*)d_in[9];
    const float* fc1w   = (const float*)d_in[10];
    const float* fc1b   = (const float*)d_in[11];
    const float* fc2w   = (const float*)d_in[12];
    const float* fc2b   = (const float*)d_in[13];
    const float* fc3w   = (const float*)d_in[14];
    const float* fc3b   = (const float*)d_in[15];

    const int N = in_sizes[0] / 130;
    const int E = in_sizes[1] / 2;
    const int total = E + N;
    float* out = (float*)d_out;

    // ---- workspace layout ----
    float* ws = (float*)d_ws;
    size_t off = 0;
    float* h      = ws + off; off += (size_t)N * 64;
    float* x3     = ws + off; off += (size_t)N * 64;
    float* alS    = ws + off; off += (size_t)N;
    float* alD    = ws + off; off += (size_t)N;
    float* u1     = ws + off; off += 512;
    float* u2     = ws + off; off += 512;
    float* cb     = ws + off; off += 512;
    int*   deg    = (int*)(ws + off); off += (size_t)N;
    int*   rowptr = (int*)(ws + off); off += (size_t)N;
    int*   cursor = (int*)(ws + off); off += (size_t)N;
    int*   bsums  = (int*)(ws + off); off += 512;
    int*   srcs   = (int*)(ws + off); off += (size_t)total;
    float* exv    = ws + off;         off += (size_t)total;
    unsigned short* gatHi = (unsigned short*)(ws + off); off += 4096;   // 64*128
    unsigned short* gatLo = (unsigned short*)(ws + off); off += 4096;
    unsigned short* f1Hi  = (unsigned short*)(ws + off); off += 12288;  // 384*64
    unsigned short* f1Lo  = (unsigned short*)(ws + off); off += 12288;
    unsigned short* f2Hi  = (unsigned short*)(ws + off); off += 24576;  // 128*384
    unsigned short* f2Lo  = (unsigned short*)(ws + off); off += 24576;
    unsigned short* f3Hi  = (unsigned short*)(ws + off); off += 4096;   // 64*128
    unsigned short* f3Lo  = (unsigned short*)(ws + off); off += 4096;

    hipMemsetAsync(deg, 0, (size_t)N * sizeof(int), stream);

    prep_u<<<3, 128, 0, stream>>>(w1, b1, w2, b2, fc1w, fc1b, u1, u2, cb);
    split_w<<<(128 * 64 + 255) / 256, 256, 0, stream>>>(gat_w, 128, 64, 64, gatHi, gatLo);
    split_w<<<(64 * 384 + 255) / 256, 256, 0, stream>>>(fc1w + (size_t)128 * 384, 64, 384, 384, f1Hi, f1Lo);
    split_w<<<(384 * 128 + 255) / 256, 256, 0, stream>>>(fc2w, 384, 128, 128, f2Hi, f2Lo);
    split_w<<<(128 * 64 + 255) / 256, 256, 0, stream>>>(fc3w, 128, 64, 64, f3Hi, f3Lo);

    // h = x[:,2:] @ gat_w  + alpha_s/alpha_d fold
    hproj_kernel<<<(N + 127) / 128, 256, 0, stream>>>(x, gatHi, gatLo,
                                                      gat_as, gat_ad, h, alS, alD, N);

    // CSR build
    count_kernel<<<(total + 255) / 256, 256, 0, stream>>>(ei, E, N, deg);
    int NB = (N + 2047) / 2048;
    scan_blk<<<NB, 256, 0, stream>>>(deg, rowptr, bsums, N);
    scan_top<<<1, 256, 0, stream>>>(bsums, NB);
    scan_add<<<(N + 255) / 256, 256, 0, stream>>>(rowptr, cursor, bsums, N);
    scatter_kernel<<<(total + 255) / 256, 256, 0, stream>>>(ei, E, N, alS, alD,
                                                            cursor, srcs, exv);

    aggregate_kernel<<<(N + 3) / 4, 256, 0, stream>>>(rowptr, cursor, srcs, exv,
                                                      h, gat_b, x3, N);

    // fused MLP: fc1 -> fc2 -> fc3
    fused_mlp<<<(N + 31) / 32, 256, 0, stream>>>(x3, x,
                                                 f1Hi, f1Lo, f2Hi, f2Lo, f3Hi, f3Lo,
                                                 cb, u1, u2, fc2b, fc3b, out, N);
}

// Round 5
// 525.909 us; speedup vs baseline: 2.6779x; 1.0862x over previous
//
#include <hip/hip_runtime.h>
#include <math.h>

#define NSLOPE 0.2f

typedef __attribute__((ext_vector_type(8))) short  bf16x8;
typedef __attribute__((ext_vector_type(4))) float  floatx4;

__device__ __forceinline__ unsigned short f2bf(float f) {
    unsigned u = __builtin_bit_cast(unsigned, f);
    u += 0x7fff + ((u >> 16) & 1);          // RNE
    return (unsigned short)(u >> 16);
}
__device__ __forceinline__ float bf2f(unsigned short h) {
    unsigned u = (unsigned)h << 16;
    return __builtin_bit_cast(float, u);
}

// split 8 fp32 -> hi/lo bf16x8
__device__ __forceinline__ void split8(const float* v, bf16x8& hi, bf16x8& lo) {
#pragma unroll
    for (int j = 0; j < 8; j++) {
        unsigned short h = f2bf(v[j]);
        hi[j] = (short)h;
        lo[j] = (short)f2bf(v[j] - bf2f(h));
    }
}

// unpack 8 interleaved u32 ((lo<<16)|hi) -> hi/lo bf16x8
__device__ __forceinline__ void unpack8(uint4 a, uint4 b, bf16x8& hi, bf16x8& lo) {
    unsigned w[8] = {a.x, a.y, a.z, a.w, b.x, b.y, b.z, b.w};
#pragma unroll
    for (int j = 0; j < 8; j++) {
        hi[j] = (short)(w[j] & 0xFFFFu);
        lo[j] = (short)(w[j] >> 16);
    }
}

// ============================================================
// h-projection + alpha fold (unchanged from R4)
// ============================================================
__global__ __launch_bounds__(256, 2)
void hproj_kernel(const float* __restrict__ x,
                  const unsigned short* __restrict__ Bhi,
                  const unsigned short* __restrict__ Blo,
                  const float* __restrict__ asrc, const float* __restrict__ adst,
                  float* __restrict__ h, float* __restrict__ alS,
                  float* __restrict__ alD, int M)
{
    const int lane = threadIdx.x & 63;
    const int wv   = threadIdx.x >> 6;
    const int l15  = lane & 15;
    const int quad = lane >> 4;
    const int m0   = blockIdx.x * 128 + wv * 32;

    floatx4 acc[2][4];
#pragma unroll
    for (int mt = 0; mt < 2; mt++)
#pragma unroll
        for (int nt = 0; nt < 4; nt++) acc[mt][nt] = (floatx4){0.f, 0.f, 0.f, 0.f};

    int r0 = m0 + l15;      if (r0 >= M) r0 = M - 1;
    int r1 = m0 + 16 + l15; if (r1 >= M) r1 = M - 1;
    const float* a0 = x + (size_t)r0 * 130 + 2 + quad * 8;
    const float* a1 = x + (size_t)r1 * 130 + 2 + quad * 8;

#pragma unroll
    for (int kt = 0; kt < 4; kt++) {
        const int kb = kt * 32;
        float av[2][8];
#pragma unroll
        for (int j = 0; j < 4; j++) {
            float2 q0 = *(const float2*)(a0 + kb + 2 * j);
            float2 q1 = *(const float2*)(a1 + kb + 2 * j);
            av[0][2 * j] = q0.x; av[0][2 * j + 1] = q0.y;
            av[1][2 * j] = q1.x; av[1][2 * j + 1] = q1.y;
        }
        bf16x8 ah[2], al[2];
        split8(av[0], ah[0], al[0]);
        split8(av[1], ah[1], al[1]);
#pragma unroll
        for (int nt = 0; nt < 4; nt++) {
            const size_t boff = (size_t)(nt * 16 + l15) * 128 + kb + quad * 8;
            bf16x8 bh = *(const bf16x8*)(Bhi + boff);
            bf16x8 bl = *(const bf16x8*)(Blo + boff);
#pragma unroll
            for (int mt = 0; mt < 2; mt++) {
                acc[mt][nt] = __builtin_amdgcn_mfma_f32_16x16x32_bf16(ah[mt], bh, acc[mt][nt], 0, 0, 0);
                acc[mt][nt] = __builtin_amdgcn_mfma_f32_16x16x32_bf16(ah[mt], bl, acc[mt][nt], 0, 0, 0);
                acc[mt][nt] = __builtin_amdgcn_mfma_f32_16x16x32_bf16(al[mt], bh, acc[mt][nt], 0, 0, 0);
            }
        }
    }

    float as4[4], ad4[4];
#pragma unroll
    for (int nt = 0; nt < 4; nt++) {
        as4[nt] = asrc[nt * 16 + l15];
        ad4[nt] = adst[nt * 16 + l15];
    }

    float ps[2][4], pd[2][4];
#pragma unroll
    for (int mt = 0; mt < 2; mt++) {
#pragma unroll
        for (int r = 0; r < 4; r++) {
            int row = m0 + mt * 16 + quad * 4 + r;
            float s = 0.f, d = 0.f;
#pragma unroll
            for (int nt = 0; nt < 4; nt++) {
                float v = acc[mt][nt][r];
                s += v * as4[nt];
                d += v * ad4[nt];
                if (row < M) h[(size_t)row * 64 + nt * 16 + l15] = v;
            }
            ps[mt][r] = s; pd[mt][r] = d;
        }
    }
#pragma unroll
    for (int mt = 0; mt < 2; mt++)
#pragma unroll
        for (int r = 0; r < 4; r++) {
#pragma unroll
            for (int msk = 1; msk < 16; msk <<= 1) {
                ps[mt][r] += __shfl_xor(ps[mt][r], msk);
                pd[mt][r] += __shfl_xor(pd[mt][r], msk);
            }
        }
    if (l15 == 0) {
#pragma unroll
        for (int mt = 0; mt < 2; mt++)
#pragma unroll
            for (int r = 0; r < 4; r++) {
                int row = m0 + mt * 16 + quad * 4 + r;
                if (row < M) { alS[row] = ps[mt][r]; alD[row] = pd[mt][r]; }
            }
    }
}

// ============================================================
// Fused MLP v2: h1 stored as bf16-HI ONLY in LDS (25.1 KB) ->
// 6 blocks/CU, direct ds_read_b128 A-frags for fc2 (no unpack),
// fc2 = 2-term split (A_hi*(B_hi+B_lo)). h2 kept hi+lo (interleaved
// u32) in the same reused buffer. fc1 per-nt epilogue keeps VGPR
// pressure low for __launch_bounds__(256,6).
// ============================================================
__global__ __launch_bounds__(256, 6)
void fused_mlp(const float* __restrict__ x3,
               const float* __restrict__ x,
               const unsigned short* __restrict__ f1Hi, const unsigned short* __restrict__ f1Lo,
               const unsigned short* __restrict__ f2Hi, const unsigned short* __restrict__ f2Lo,
               const unsigned short* __restrict__ f3Hi, const unsigned short* __restrict__ f3Lo,
               const float* __restrict__ cb, const float* __restrict__ u1,
               const float* __restrict__ u2, const float* __restrict__ fc2b,
               const float* __restrict__ fc3b,
               float* __restrict__ out, int M)
{
    __shared__ unsigned int smem[6272];                  // 25088 B
    unsigned short* h1s = (unsigned short*)smem;          // [32][392] bf16-hi
    const int lane = threadIdx.x & 63;
    const int wv   = threadIdx.x >> 6;
    const int l15  = lane & 15;
    const int quad = lane >> 4;
    const int m0   = blockIdx.x * 32;

    // ---- fc1 A-frags from x3 (K=64), split hi/lo ----
    bf16x8 ah[2][2], al[2][2];
    {
        int r0 = m0 + l15;      if (r0 >= M) r0 = M - 1;
        int r1 = m0 + 16 + l15; if (r1 >= M) r1 = M - 1;
        const float* a0 = x3 + (size_t)r0 * 64 + quad * 8;
        const float* a1 = x3 + (size_t)r1 * 64 + quad * 8;
#pragma unroll
        for (int kt = 0; kt < 2; kt++) {
            float av[2][8];
            float4 q0a = *(const float4*)(a0 + kt * 32);
            float4 q0b = *(const float4*)(a0 + kt * 32 + 4);
            float4 q1a = *(const float4*)(a1 + kt * 32);
            float4 q1b = *(const float4*)(a1 + kt * 32 + 4);
            av[0][0]=q0a.x; av[0][1]=q0a.y; av[0][2]=q0a.z; av[0][3]=q0a.w;
            av[0][4]=q0b.x; av[0][5]=q0b.y; av[0][6]=q0b.z; av[0][7]=q0b.w;
            av[1][0]=q1a.x; av[1][1]=q1a.y; av[1][2]=q1a.z; av[1][3]=q1a.w;
            av[1][4]=q1b.x; av[1][5]=q1b.y; av[1][6]=q1b.z; av[1][7]=q1b.w;
            split8(av[0], ah[0][kt], al[0][kt]);
            split8(av[1], ah[1][kt], al[1][kt]);
        }
    }

    // rank-1 row scalars (x[:,0], x[:,1]) for this lane's epilogue rows
    float xv0[2][4], xv1[2][4];
#pragma unroll
    for (int mt = 0; mt < 2; mt++)
#pragma unroll
        for (int r = 0; r < 4; r++) {
            int row = m0 + mt * 16 + quad * 4 + r;
            float2 xv = {0.f, 0.f};
            if (row < M) xv = *(const float2*)(x + (size_t)row * 130);
            xv0[mt][r] = xv.x; xv1[mt][r] = xv.y;
        }

    // ---- fc1: per-nt compute + immediate epilogue -> h1s (hi only) ----
    const int colw1 = wv * 96;
#pragma unroll
    for (int nt = 0; nt < 6; nt++) {
        floatx4 acc1[2];
        acc1[0] = (floatx4){0.f, 0.f, 0.f, 0.f};
        acc1[1] = (floatx4){0.f, 0.f, 0.f, 0.f};
        const int col = colw1 + nt * 16 + l15;
        const size_t cb0 = (size_t)col * 64 + quad * 8;
#pragma unroll
        for (int kt = 0; kt < 2; kt++) {
            bf16x8 bh = *(const bf16x8*)(f1Hi + cb0 + kt * 32);
            bf16x8 bl = *(const bf16x8*)(f1Lo + cb0 + kt * 32);
#pragma unroll
            for (int mt = 0; mt < 2; mt++) {
                acc1[mt] = __builtin_amdgcn_mfma_f32_16x16x32_bf16(ah[mt][kt], bh, acc1[mt], 0, 0, 0);
                acc1[mt] = __builtin_amdgcn_mfma_f32_16x16x32_bf16(ah[mt][kt], bl, acc1[mt], 0, 0, 0);
                acc1[mt] = __builtin_amdgcn_mfma_f32_16x16x32_bf16(al[mt][kt], bh, acc1[mt], 0, 0, 0);
            }
        }
        float c0 = cb[col], uu1 = u1[col], uu2 = u2[col];
#pragma unroll
        for (int mt = 0; mt < 2; mt++)
#pragma unroll
            for (int r = 0; r < 4; r++) {
                float v = acc1[mt][r] + c0 + xv0[mt][r] * uu1 + xv1[mt][r] * uu2;
                v = v > 0.f ? v : 0.f;
                h1s[(mt * 16 + quad * 4 + r) * 392 + col] = f2bf(v);
            }
    }
    __syncthreads();

    // ---- fc2: K=384, A-frags direct b128 from h1s (hi only) ----
    floatx4 acc2[2][2];
#pragma unroll
    for (int mt = 0; mt < 2; mt++)
#pragma unroll
        for (int nt = 0; nt < 2; nt++) acc2[mt][nt] = (floatx4){0.f, 0.f, 0.f, 0.f};
#pragma unroll 4
    for (int kt = 0; kt < 12; kt++) {
        bf16x8 a2[2];
#pragma unroll
        for (int mt = 0; mt < 2; mt++)
            a2[mt] = *(const bf16x8*)&h1s[(mt * 16 + l15) * 392 + kt * 32 + quad * 8];
#pragma unroll
        for (int nt = 0; nt < 2; nt++) {
            const size_t boff = (size_t)(wv * 32 + nt * 16 + l15) * 384 + kt * 32 + quad * 8;
            bf16x8 bh = *(const bf16x8*)(f2Hi + boff);
            bf16x8 bl = *(const bf16x8*)(f2Lo + boff);
#pragma unroll
            for (int mt = 0; mt < 2; mt++) {
                acc2[mt][nt] = __builtin_amdgcn_mfma_f32_16x16x32_bf16(a2[mt], bh, acc2[mt][nt], 0, 0, 0);
                acc2[mt][nt] = __builtin_amdgcn_mfma_f32_16x16x32_bf16(a2[mt], bl, acc2[mt][nt], 0, 0, 0);
            }
        }
    }
    __syncthreads();   // all h1 reads done before overwrite

    // ---- fc2 epilogue -> h2 (hi|lo interleaved u32), stride 132 ----
#pragma unroll
    for (int mt = 0; mt < 2; mt++)
#pragma unroll
        for (int r = 0; r < 4; r++) {
            int rl = mt * 16 + quad * 4 + r;
#pragma unroll
            for (int nt = 0; nt < 2; nt++) {
                int col = wv * 32 + nt * 16 + l15;
                float v = acc2[mt][nt][r] + fc2b[col];
                v = v > 0.f ? v : 0.f;
                unsigned short hi = f2bf(v);
                unsigned short lo = f2bf(v - bf2f(hi));
                smem[rl * 132 + col] = (unsigned)hi | ((unsigned)lo << 16);
            }
        }
    __syncthreads();

    // ---- fc3: K=128 from h2 (hi+lo), 3-term split ----
    floatx4 acc3[2];
    acc3[0] = (floatx4){0.f, 0.f, 0.f, 0.f};
    acc3[1] = (floatx4){0.f, 0.f, 0.f, 0.f};
#pragma unroll
    for (int kt = 0; kt < 4; kt++) {
        bf16x8 a3h[2], a3l[2];
#pragma unroll
        for (int mt = 0; mt < 2; mt++) {
            int base = (mt * 16 + l15) * 132 + kt * 32 + quad * 8;
            uint4 wa = *(const uint4*)&smem[base];
            uint4 wb = *(const uint4*)&smem[base + 4];
            unpack8(wa, wb, a3h[mt], a3l[mt]);
        }
        const size_t boff = (size_t)(wv * 16 + l15) * 128 + kt * 32 + quad * 8;
        bf16x8 bh = *(const bf16x8*)(f3Hi + boff);
        bf16x8 bl = *(const bf16x8*)(f3Lo + boff);
#pragma unroll
        for (int mt = 0; mt < 2; mt++) {
            acc3[mt] = __builtin_amdgcn_mfma_f32_16x16x32_bf16(a3h[mt], bh, acc3[mt], 0, 0, 0);
            acc3[mt] = __builtin_amdgcn_mfma_f32_16x16x32_bf16(a3h[mt], bl, acc3[mt], 0, 0, 0);
            acc3[mt] = __builtin_amdgcn_mfma_f32_16x16x32_bf16(a3l[mt], bh, acc3[mt], 0, 0, 0);
        }
    }
    {
        int col = wv * 16 + l15;
        float bv = fc3b[col];
#pragma unroll
        for (int mt = 0; mt < 2; mt++)
#pragma unroll
            for (int r = 0; r < 4; r++) {
                int row = m0 + mt * 16 + quad * 4 + r;
                if (row < M) out[(size_t)row * 64 + col] = acc3[mt][r] + bv;
            }
    }
}

// ============================================================
// Pre-split weights -> hi/lo bf16 planes, [n][k] layout
// ============================================================
__global__ void split_w(const float* __restrict__ W, int K, int Nc, int ldw,
                        unsigned short* __restrict__ hi, unsigned short* __restrict__ lo)
{
    int idx = blockIdx.x * 256 + threadIdx.x;
    if (idx >= K * Nc) return;
    int n = idx / K, k = idx - n * K;
    float v = W[(size_t)k * ldw + n];
    unsigned short h = f2bf(v);
    hi[idx] = h;
    lo[idx] = f2bf(v - bf2f(h));
}

// ============================================================
// rank-1 folds of x1/x2 paths into fc1
// ============================================================
__global__ void prep_u(const float* __restrict__ w1, const float* __restrict__ b1,
                       const float* __restrict__ w2, const float* __restrict__ b2,
                       const float* __restrict__ fc1w, const float* __restrict__ fc1b,
                       float* __restrict__ u1, float* __restrict__ u2, float* __restrict__ cb)
{
    int j = threadIdx.x + blockIdx.x * blockDim.x;
    if (j >= 384) return;
    float s1 = 0.f, s2 = 0.f, c = fc1b[j];
    for (int k = 0; k < 64; k++) {
        float wv = fc1w[k * 384 + j];
        s1 += w1[k] * wv; c += b1[k] * wv;
    }
    for (int k = 0; k < 64; k++) {
        float wv = fc1w[(64 + k) * 384 + j];
        s2 += w2[k] * wv; c += b2[k] * wv;
    }
    u1[j] = s1; u2[j] = s2; cb[j] = c;
}

// ============================================================
// CSR build
// ============================================================
__global__ __launch_bounds__(256)
void count_kernel(const int* __restrict__ ei, int E, int N, int* __restrict__ deg)
{
    int t = blockIdx.x * 256 + threadIdx.x;
    int total = E + N;
    if (t >= total) return;
    int d = (t < E) ? ei[E + t] : (t - E);
    atomicAdd(&deg[d], 1);
}

__global__ __launch_bounds__(256)
void scan_blk(const int* __restrict__ deg, int* __restrict__ rowptr,
              int* __restrict__ bsums, int N)
{
    __shared__ int sh[256];
    int b = blockIdx.x, t = threadIdx.x;
    int base = b * 2048 + t * 8;
    int v[8]; int s = 0;
#pragma unroll
    for (int j = 0; j < 8; j++) {
        v[j] = (base + j < N) ? deg[base + j] : 0;
        s += v[j];
    }
    sh[t] = s; __syncthreads();
#pragma unroll
    for (int off = 1; off < 256; off <<= 1) {
        int x = (t >= off) ? sh[t - off] : 0;
        __syncthreads();
        sh[t] += x;
        __syncthreads();
    }
    if (t == 255) bsums[b] = sh[255];
    int run = (t > 0) ? sh[t - 1] : 0;
#pragma unroll
    for (int j = 0; j < 8; j++) {
        if (base + j < N) rowptr[base + j] = run;
        run += v[j];
    }
}

__global__ void scan_top(int* __restrict__ bsums, int NB)
{
    __shared__ int sh[256];
    int t = threadIdx.x;
    sh[t] = (t < NB) ? bsums[t] : 0;
    __syncthreads();
#pragma unroll
    for (int off = 1; off < 256; off <<= 1) {
        int x = (t >= off) ? sh[t - off] : 0;
        __syncthreads();
        sh[t] += x;
        __syncthreads();
    }
    if (t < NB) bsums[t] = (t > 0) ? sh[t - 1] : 0;
}

__global__ __launch_bounds__(256)
void scan_add(int* __restrict__ rowptr, int* __restrict__ cursor,
              const int* __restrict__ bsums, int N)
{
    int i = blockIdx.x * 256 + threadIdx.x;
    if (i >= N) return;
    int v = rowptr[i] + bsums[i >> 11];
    rowptr[i] = v;
    cursor[i] = v;
}

// scatter (src, exp) packed as ONE uint2 per edge
__global__ __launch_bounds__(256)
void scatter_kernel(const int* __restrict__ ei, int E, int N,
                    const float* __restrict__ alS, const float* __restrict__ alD,
                    int* __restrict__ cursor, uint2* __restrict__ sev)
{
    int t = blockIdx.x * 256 + threadIdx.x;
    int total = E + N;
    if (t >= total) return;
    int s, d;
    if (t < E) { s = ei[t]; d = ei[E + t]; }
    else       { s = t - E; d = s; }
    float v = alS[s] + alD[d];
    v = v > 0.f ? v : NSLOPE * v;
    float ex = expf(v);
    int pos = atomicAdd(&cursor[d], 1);
    sev[pos] = make_uint2((unsigned)s, __builtin_bit_cast(unsigned, ex));
}

// ============================================================
// Gather-aggregate + normalize + bias -> x3; 4x unrolled gathers
// ============================================================
__global__ __launch_bounds__(256)
void aggregate_kernel(const int* __restrict__ rowptr, const int* __restrict__ cursor,
                      const uint2* __restrict__ sev,
                      const float* __restrict__ h, const float* __restrict__ gatb,
                      float* __restrict__ x3, int N)
{
    int node = blockIdx.x * 4 + (threadIdx.x >> 6);
    int lane = threadIdx.x & 63;
    if (node >= N) return;
    int start = rowptr[node];
    int end   = cursor[node];
    float accv = 0.f, den = 0.f;
    for (int p = start; p < end; p += 64) {
        int idx = p + lane;
        uint2 se = make_uint2(0u, 0u);
        if (idx < end) se = sev[idx];
        int si = (int)se.x;
        float ex = __builtin_bit_cast(float, se.y);
        int cnt = end - p; if (cnt > 64) cnt = 64;
        int j = 0;
        for (; j + 4 <= cnt; j += 4) {
            int   s0 = __shfl(si, j),     s1 = __shfl(si, j + 1);
            int   s2 = __shfl(si, j + 2), s3 = __shfl(si, j + 3);
            float e0 = __shfl(ex, j),     e1 = __shfl(ex, j + 1);
            float e2 = __shfl(ex, j + 2), e3 = __shfl(ex, j + 3);
            float h0 = h[(size_t)s0 * 64 + lane];
            float h1 = h[(size_t)s1 * 64 + lane];
            float h2 = h[(size_t)s2 * 64 + lane];
            float h3 = h[(size_t)s3 * 64 + lane];
            den  += (e0 + e1) + (e2 + e3);
            accv += e0 * h0; accv += e1 * h1; accv += e2 * h2; accv += e3 * h3;
        }
        for (; j < cnt; j++) {
            int   sj = __shfl(si, j);
            float ej = __shfl(ex, j);
            den += ej;
            accv += ej * h[(size_t)sj * 64 + lane];
        }
    }
    x3[(size_t)node * 64 + lane] = accv / (den + 1e-16f) + gatb[lane];
}

extern "C" void kernel_launch(void* const* d_in, const int* in_sizes, int n_in,
                              void* d_out, int out_size, void* d_ws, size_t ws_size,
                              hipStream_t stream)
{
    const float* x      = (const float*)d_in[0];
    const int*   ei     = (const int*)d_in[1];
    const float* w1     = (const float*)d_in[2];
    const float* b1     = (const float*)d_in[3];
    const float* w2     = (const float*)d_in[4];
    const float* b2     = (const float*)d_in[5];
    const float* gat_w  = (const float*)d_in[6];
    const float* gat_as = (const float*)d_in[7];
    const float* gat_ad = (const float*)d_in[8];
    const float* gat_b  = (const float*)d_in[9];
    const float* fc1w   = (const float*)d_in[10];
    const float* fc1b   = (const float*)d_in[11];
    const float* fc2w   = (const float*)d_in[12];
    const float* fc2b   = (const float*)d_in[13];
    const float* fc3w   = (const float*)d_in[14];
    const float* fc3b   = (const float*)d_in[15];

    const int N = in_sizes[0] / 130;
    const int E = in_sizes[1] / 2;
    const int total = E + N;
    float* out = (float*)d_out;

    // ---- workspace layout ----
    float* ws = (float*)d_ws;
    size_t off = 0;
    float* h      = ws + off; off += (size_t)N * 64;
    float* x3     = ws + off; off += (size_t)N * 64;
    float* alS    = ws + off; off += (size_t)N;
    float* alD    = ws + off; off += (size_t)N;
    float* u1     = ws + off; off += 512;
    float* u2     = ws + off; off += 512;
    float* cb     = ws + off; off += 512;
    int*   deg    = (int*)(ws + off); off += (size_t)N;
    int*   rowptr = (int*)(ws + off); off += (size_t)N;
    int*   cursor = (int*)(ws + off); off += (size_t)N;
    int*   bsums  = (int*)(ws + off); off += 512;
    uint2* sev    = (uint2*)(ws + off); off += (size_t)total * 2;
    unsigned short* gatHi = (unsigned short*)(ws + off); off += 4096;   // 64*128
    unsigned short* gatLo = (unsigned short*)(ws + off); off += 4096;
    unsigned short* f1Hi  = (unsigned short*)(ws + off); off += 12288;  // 384*64
    unsigned short* f1Lo  = (unsigned short*)(ws + off); off += 12288;
    unsigned short* f2Hi  = (unsigned short*)(ws + off); off += 24576;  // 128*384
    unsigned short* f2Lo  = (unsigned short*)(ws + off); off += 24576;
    unsigned short* f3Hi  = (unsigned short*)(ws + off); off += 4096;   // 64*128
    unsigned short* f3Lo  = (unsigned short*)(ws + off); off += 4096;

    hipMemsetAsync(deg, 0, (size_t)N * sizeof(int), stream);

    prep_u<<<3, 128, 0, stream>>>(w1, b1, w2, b2, fc1w, fc1b, u1, u2, cb);
    split_w<<<(128 * 64 + 255) / 256, 256, 0, stream>>>(gat_w, 128, 64, 64, gatHi, gatLo);
    split_w<<<(64 * 384 + 255) / 256, 256, 0, stream>>>(fc1w + (size_t)128 * 384, 64, 384, 384, f1Hi, f1Lo);
    split_w<<<(384 * 128 + 255) / 256, 256, 0, stream>>>(fc2w, 384, 128, 128, f2Hi, f2Lo);
    split_w<<<(128 * 64 + 255) / 256, 256, 0, stream>>>(fc3w, 128, 64, 64, f3Hi, f3Lo);

    // h = x[:,2:] @ gat_w  + alpha_s/alpha_d fold
    hproj_kernel<<<(N + 127) / 128, 256, 0, stream>>>(x, gatHi, gatLo,
                                                      gat_as, gat_ad, h, alS, alD, N);

    // CSR build
    count_kernel<<<(total + 255) / 256, 256, 0, stream>>>(ei, E, N, deg);
    int NB = (N + 2047) / 2048;
    scan_blk<<<NB, 256, 0, stream>>>(deg, rowptr, bsums, N);
    scan_top<<<1, 256, 0, stream>>>(bsums, NB);
    scan_add<<<(N + 255) / 256, 256, 0, stream>>>(rowptr, cursor, bsums, N);
    scatter_kernel<<<(total + 255) / 256, 256, 0, stream>>>(ei, E, N, alS, alD,
                                                            cursor, sev);

    aggregate_kernel<<<(N + 3) / 4, 256, 0, stream>>>(rowptr, cursor, sev,
                                                      h, gat_b, x3, N);

    // fused MLP: fc1 -> fc2 -> fc3
    fused_mlp<<<(N + 31) / 32, 256, 0, stream>>>(x3, x,
                                                 f1Hi, f1Lo, f2Hi, f2Lo, f3Hi, f3Lo,
                                                 cb, u1, u2, fc2b, fc3b, out, N);
}